// Round 8
// baseline (665.554 us; speedup 1.0000x reference)
//
#include <hip/hip_runtime.h>
#include <hip/hip_bf16.h>

#define N_FULL 200000
#define N_SUB  80000
#define E_NUM  800000
#define IN_DIM 128
#define HD     128
#define LMAX   5

#define NB_E (E_NUM / 256)          // 3125
#define WCOMB_BLKS 128

// ---------------- count in-degree ----------------

__global__ void count_deg(const int* __restrict__ dst, int* __restrict__ cnt) {
    int i = blockIdx.x * blockDim.x + threadIdx.x;
    if (i < E_NUM) atomicAdd(&cnt[dst[i]], 1);
}

// ---------------- single-block scan (cnt -> offs, x4 vectorized) + level init ----------------

__global__ __launch_bounds__(1024) void scan_plus(const int* __restrict__ cnt,
                                                  int* __restrict__ offs,
                                                  int* __restrict__ level) {
    __shared__ int wsum[16];
    int t = threadIdx.x, lane = t & 63, wv = t >> 6;
    int carry = 0;
    const int NCH = (N_SUB + 4095) / 4096;   // 20 (N_SUB % 4 == 0)
    for (int c = 0; c < NCH; ++c) {
        int i4 = c * 4096 + t * 4;
        int4 v = make_int4(0, 0, 0, 0);
        if (i4 < N_SUB) v = *(const int4*)(cnt + i4);
        int s = v.x + v.y + v.z + v.w;
        int x = s;
#pragma unroll
        for (int off = 1; off < 64; off <<= 1) {
            int y = __shfl_up(x, off);
            if (lane >= off) x += y;
        }
        if (lane == 63) wsum[wv] = x;
        __syncthreads();
        int wbase = 0, total = 0;
#pragma unroll
        for (int w2 = 0; w2 < 16; ++w2) {
            int s2 = wsum[w2];
            if (w2 < wv) wbase += s2;
            total += s2;
        }
        if (i4 < N_SUB) {
            int e = carry + wbase + x - s;
            *(int4*)(offs + i4) = make_int4(e, e + v.x, e + v.x + v.y, e + v.x + v.y + v.z);
            int4 lv = make_int4(7, 7, 7, 7);
            if (i4 == 0) { lv.x = 0; lv.y = 0; }
            *(int4*)(level + i4) = lv;
        }
        carry += total;
        __syncthreads();
    }
    if (t == 0) offs[N_SUB] = E_NUM;
}

// ---------------- fill CSR (atomicSub on degree) + wcomb in spare blocks ----------------

__global__ __launch_bounds__(256) void fill_wcomb(
    const int* __restrict__ esrc, const int* __restrict__ edst,
    const int* __restrict__ offs, int* __restrict__ cnt, int* __restrict__ csr,
    const float* __restrict__ W_l, const float* __restrict__ W_r,
    const float* __restrict__ W_in, const float* __restrict__ b_in,
    const float* __restrict__ b_l,
    float* __restrict__ Wc1, float* __restrict__ Wc2, float* __restrict__ bc) {
    int b = blockIdx.x;
    int t = threadIdx.x;
    if (b < NB_E) {
        int i = b * 256 + t;
        int d = edst[i];
        int p = atomicSub(&cnt[d], 1) - 1;   // unique slot in [0, deg)
        csr[offs[d] + p] = esrc[i];
    } else {
        __shared__ float sf[256];
        int f = b - NB_E;                    // 0..127
        if (t < 128) sf[t] = W_l[f * 128 + t];
        else sf[t] = W_r[f * 128 + (t - 128)];
        __syncthreads();
        int c = t & 127, p = t >> 7;
        const float* wrow = p ? (sf + 128) : sf;
        float acc = 0.f;
#pragma unroll 8
        for (int j = 0; j < 128; ++j)
            acc = fmaf(wrow[j], W_in[j * 128 + c], acc);
        (p ? Wc2 : Wc1)[f * 128 + c] = acc;
        if (t < 64) {
            float pa = (sf[t] + sf[128 + t]) * b_in[t] +
                       (sf[t + 64] + sf[192 + t]) * b_in[t + 64];
            for (int off = 32; off; off >>= 1) pa += __shfl_down(pa, off);
            if (t == 0) bc[f] = pa + b_l[f];
        }
    }
}

// ---------------- single-block frontier BFS, wave-aggregated append ----------------

__global__ __launch_bounds__(1024) void bfs_compact(
    const int* __restrict__ offs, const int* __restrict__ csr,
    int* __restrict__ level, int* __restrict__ order, int* __restrict__ cum) {
    __shared__ int qtail_s, qcnt;
    int t = threadIdx.x, lane = t & 63;
    if (t == 0) { order[0] = 0; order[1] = 1; qtail_s = 2; qcnt = 0; cum[0] = 2; }
    __syncthreads();
    int qhead = 0, qtail = 2;
    for (int lvl = 0; lvl < 4; ++lvl) {
        for (int idx = qhead + t; idx < qtail; idx += 1024) {
            int v = order[idx];
            int beg = offs[v], end = offs[v + 1];
            for (int j = beg; j < end; ++j) {
                int u = csr[j];
                bool succ = false;
                if (level[u] == 7 && atomicMin(&level[u], lvl + 1) == 7) succ = true;
                unsigned long long m = __ballot(succ);
                if (m) {
                    int rank = (int)__popcll(m & ((1ull << lane) - 1ull));
                    int leader = __ffsll((long long)m) - 1;
                    int base = 0;
                    if (lane == leader) base = atomicAdd(&qcnt, (int)__popcll(m));
                    base = __shfl(base, leader);
                    if (succ) order[qtail + base + rank] = u;
                }
            }
        }
        __syncthreads();
        if (t == 0) { qtail_s = qtail + qcnt; qcnt = 0; cum[lvl + 1] = qtail_s; }
        __syncthreads();
        qhead = qtail;
        qtail = qtail_s;
        __syncthreads();
    }
}

// ---------------- mean aggregation (device fn, used by tail) ----------------

__device__ void dev_aggregate(
    const float* __restrict__ H, float* __restrict__ Out,
    const int* __restrict__ offs, const int* __restrict__ csr,
    const int* __restrict__ order, int M, const int* __restrict__ srcmap,
    int bid0, int nb) {
    int ngroups = (M + 3) >> 2;
    int wid = threadIdx.x >> 6, lane = threadIdx.x & 63;
    for (int g = bid0; g < ngroups; g += nb) {
        int ni = g * 4 + wid;
        if (ni >= M) continue;
        int node = order[ni];
        int beg = offs[node], end = offs[node + 1];
        float ax = 0.f, ay = 0.f, bx = 0.f, by = 0.f;
        int j = beg;
        for (; j + 1 < end; j += 2) {
            int s0 = csr[j], s1 = csr[j + 1];
            int r0 = srcmap ? srcmap[s0] : s0;
            int r1 = srcmap ? srcmap[s1] : s1;
            float2 v0 = *(const float2*)(H + (size_t)r0 * HD + lane * 2);
            float2 v1 = *(const float2*)(H + (size_t)r1 * HD + lane * 2);
            ax += v0.x; ay += v0.y;
            bx += v1.x; by += v1.y;
        }
        if (j < end) {
            int s0 = csr[j];
            int r0 = srcmap ? srcmap[s0] : s0;
            float2 v0 = *(const float2*)(H + (size_t)r0 * HD + lane * 2);
            ax += v0.x; ay += v0.y;
        }
        int deg = end - beg;
        float inv = 1.0f / (float)(deg > 1 ? deg : 1);
        *(float2*)(Out + (size_t)node * HD + lane * 2) =
            make_float2((ax + bx) * inv, (ay + by) * inv);
    }
}

// ---------------- head MLP on nodes 0,1 (device fn, 256 threads) ----------------

__device__ void dev_head(
    const float* __restrict__ H,
    const float* __restrict__ W_e1, const float* __restrict__ b_e1,
    const float* __restrict__ W_e2, const float* __restrict__ b_e2,
    const float* __restrict__ W_h1, const float* __restrict__ b_h1,
    const float* __restrict__ W_h2, const float* __restrict__ b_h2,
    float* __restrict__ head_out, int kidx) {

    __shared__ float feat[384];
    __shared__ float rowo[128];
    __shared__ float sc_sh;
    int t = threadIdx.x, lane = t & 63, wv = t >> 6;

    __syncthreads();
    if (t < 128) {
        float a = H[t], b = H[128 + t];
        feat[t] = a;
        feat[128 + t] = b;
        feat[256 + t] = a * b;
    }
    __syncthreads();

    for (int r = wv; r < 128; r += 4) {
        const float* wr = W_e1 + r * 384;
        float acc = 0.f;
#pragma unroll
        for (int j = 0; j < 6; ++j)
            acc += feat[lane + 64 * j] * wr[lane + 64 * j];
        for (int off = 32; off; off >>= 1) acc += __shfl_down(acc, off);
        if (lane == 0) rowo[r] = fmaxf(acc + b_e1[r], 0.f) * W_e2[r];
    }
    __syncthreads();
    if (wv == 0) {
        float v = rowo[lane] + rowo[lane + 64];
        for (int off = 32; off; off >>= 1) v += __shfl_down(v, off);
        if (lane == 0) sc_sh = v + b_e2[0];
    }
    __syncthreads();
    float score = sc_sh;

    for (int r = wv; r < 64; r += 4) {
        const float* wh = W_h1 + r * 257;
        float acc = 0.f;
#pragma unroll
        for (int j = 0; j < 4; ++j)
            acc += feat[lane + 64 * j] * wh[lane + 64 * j];
        if (lane == 0) acc += score * wh[256];
        for (int off = 32; off; off >>= 1) acc += __shfl_down(acc, off);
        if (lane == 0) rowo[r] = fmaxf(acc + b_h1[r], 0.f) * W_h2[r];
    }
    __syncthreads();
    if (wv == 0) {
        float v = rowo[lane];
        for (int off = 32; off; off >>= 1) v += __shfl_down(v, off);
        if (lane == 0) {
            float p = 1.f / (1.f + expf(-(v + b_h2[0])));
            head_out[kidx * 2 + 0] = score;
            head_out[kidx * 2 + 1] = p;
        }
    }
    __syncthreads();
}

// ---------------- tiled GEMM (device fn, used by tail) ----------------

#define GBM 64
#define GBK 32

__device__ void dev_gemm(
    const float* __restrict__ A1, const float* __restrict__ A2,
    const float* __restrict__ W1, const float* __restrict__ W2,
    const float* __restrict__ bias, float* __restrict__ Out,
    const int* __restrict__ order, const int* __restrict__ gatherA,
    const int* __restrict__ gatherB, int M, int bid0, int nb,
    const float* __restrict__ W_e1, const float* __restrict__ b_e1,
    const float* __restrict__ W_e2, const float* __restrict__ b_e2,
    const float* __restrict__ W_h1, const float* __restrict__ b_h1,
    const float* __restrict__ W_h2, const float* __restrict__ b_h2,
    float* __restrict__ head_out, int head_kidx) {

    __shared__ __align__(16) float As[GBK][68];
    __shared__ __align__(16) float Ws[GBK][132];

    int ntiles = (M + GBM - 1) / GBM;
    int tid = threadIdx.x;
    int tx = tid & 15, ty = tid >> 4;
    int r0 = ty * 4;
    int c0 = tx * 4;

    for (int tile = bid0; tile < ntiles; tile += nb) {
        int row0 = tile * GBM;

        float acc[4][8];
#pragma unroll
        for (int i = 0; i < 4; ++i)
#pragma unroll
            for (int j = 0; j < 8; ++j) acc[i][j] = 0.f;

        for (int ch = 0; ch < 8; ++ch) {
            const float* Asrc = (ch < 4) ? A1 : A2;
            const float* Wsrc = (ch < 4) ? W1 : W2;
            const int* gmap = (ch < 4) ? gatherA : gatherB;
            int kbase = (ch & 3) * GBK;

#pragma unroll
            for (int it = 0; it < 2; ++it) {
                int idx = tid + it * 256;
                int m = idx >> 3, kq = idx & 7;
                int row = row0 + m;
                float4 v = make_float4(0.f, 0.f, 0.f, 0.f);
                if (row < M) {
                    int nr = order[row];
                    int ar = gmap ? gmap[nr] : nr;
                    v = *(const float4*)(Asrc + (size_t)ar * 128 + kbase + kq * 4);
                }
                As[kq * 4 + 0][m] = v.x;
                As[kq * 4 + 1][m] = v.y;
                As[kq * 4 + 2][m] = v.z;
                As[kq * 4 + 3][m] = v.w;
            }
#pragma unroll
            for (int it = 0; it < 4; ++it) {
                int idx = tid + it * 256;
                int n = idx >> 3, kq = idx & 7;
                float4 v = *(const float4*)(Wsrc + n * 128 + kbase + kq * 4);
                Ws[kq * 4 + 0][n] = v.x;
                Ws[kq * 4 + 1][n] = v.y;
                Ws[kq * 4 + 2][n] = v.z;
                Ws[kq * 4 + 3][n] = v.w;
            }
            __syncthreads();

#pragma unroll
            for (int kk = 0; kk < GBK; ++kk) {
                float4 a  = *(const float4*)&As[kk][r0];
                float4 w0 = *(const float4*)&Ws[kk][c0];
                float4 w1 = *(const float4*)&Ws[kk][c0 + 64];
                float av[4] = {a.x, a.y, a.z, a.w};
                float wv[8] = {w0.x, w0.y, w0.z, w0.w, w1.x, w1.y, w1.z, w1.w};
#pragma unroll
                for (int i = 0; i < 4; ++i)
#pragma unroll
                    for (int j = 0; j < 8; ++j)
                        acc[i][j] = fmaf(av[i], wv[j], acc[i][j]);
            }
            __syncthreads();
        }

#pragma unroll
        for (int i = 0; i < 4; ++i) {
            int row = row0 + r0 + i;
            if (row >= M) continue;
            int nr = order[row];
            float4 o0, o1;
            o0.x = fmaxf(acc[i][0] + bias[c0 + 0], 0.f);
            o0.y = fmaxf(acc[i][1] + bias[c0 + 1], 0.f);
            o0.z = fmaxf(acc[i][2] + bias[c0 + 2], 0.f);
            o0.w = fmaxf(acc[i][3] + bias[c0 + 3], 0.f);
            o1.x = fmaxf(acc[i][4] + bias[c0 + 64], 0.f);
            o1.y = fmaxf(acc[i][5] + bias[c0 + 65], 0.f);
            o1.z = fmaxf(acc[i][6] + bias[c0 + 66], 0.f);
            o1.w = fmaxf(acc[i][7] + bias[c0 + 67], 0.f);
            *(float4*)(Out + (size_t)nr * 128 + c0) = o0;
            *(float4*)(Out + (size_t)nr * 128 + c0 + 64) = o1;
        }

        if (tile == 0 && head_kidx >= 0) {
            dev_head(Out, W_e1, b_e1, W_e2, b_e2, W_h1, b_h1, W_h2, b_h2,
                     head_out, head_kidx);
        }
    }
}

// ---------------- fused SAGE step: per-tile LDS aggregate + GEMM (+head) ----------------
// Hout[nr] = relu( mean_{u in N(nr)} Hin[map(u)] @ W1.T + Hin[map(nr)] @ W2.T + bias )
// Safe: reads Hin (stable), writes Hout (ping-pong).

__global__ __launch_bounds__(256) void sage_step(
    const float* __restrict__ Hin, float* __restrict__ Hout,
    const float* __restrict__ W1, const float* __restrict__ W2,
    const float* __restrict__ bias,
    const int* __restrict__ order, const int* __restrict__ offs,
    const int* __restrict__ csr, const int* __restrict__ srcmap,
    const int* __restrict__ cum, int lvl,
    const float* __restrict__ W_e1, const float* __restrict__ b_e1,
    const float* __restrict__ W_e2, const float* __restrict__ b_e2,
    const float* __restrict__ W_h1, const float* __restrict__ b_h1,
    const float* __restrict__ W_h2, const float* __restrict__ b_h2,
    float* __restrict__ head_out, int head_kidx) {

    __shared__ __align__(16) float aggL[GBM][132];
    __shared__ __align__(16) float As[GBK][68];
    __shared__ __align__(16) float Ws[GBK][132];

    int M = cum[lvl];
    int ntiles = (M + GBM - 1) / GBM;
    int tid = threadIdx.x;
    int lane = tid & 63, wid = tid >> 6;
    int tx = tid & 15, ty = tid >> 4;
    int r0 = ty * 4;
    int c0 = tx * 4;

    for (int tile = blockIdx.x; tile < ntiles; tile += gridDim.x) {
        int row0 = tile * GBM;

        // Phase A: aggregate this tile's 64 rows into LDS (wave per node)
        for (int q = 0; q < 16; ++q) {
            int m = wid * 16 + q;
            int row = row0 + m;
            if (row >= M) continue;
            int node = order[row];
            int beg = offs[node], end = offs[node + 1];
            float ax = 0.f, ay = 0.f, bx = 0.f, by = 0.f;
            int j = beg;
            for (; j + 1 < end; j += 2) {
                int s0 = csr[j], s1 = csr[j + 1];
                int a0 = srcmap ? srcmap[s0] : s0;
                int a1 = srcmap ? srcmap[s1] : s1;
                float2 v0 = *(const float2*)(Hin + (size_t)a0 * 128 + lane * 2);
                float2 v1 = *(const float2*)(Hin + (size_t)a1 * 128 + lane * 2);
                ax += v0.x; ay += v0.y;
                bx += v1.x; by += v1.y;
            }
            if (j < end) {
                int s0 = csr[j];
                int a0 = srcmap ? srcmap[s0] : s0;
                float2 v0 = *(const float2*)(Hin + (size_t)a0 * 128 + lane * 2);
                ax += v0.x; ay += v0.y;
            }
            int deg = end - beg;
            float inv = 1.0f / (float)(deg > 1 ? deg : 1);
            *(float2*)&aggL[m][lane * 2] = make_float2((ax + bx) * inv, (ay + by) * inv);
        }
        __syncthreads();

        // Phase B: GEMM (A1 = aggL from LDS, A2 = Hin direct)
        float acc[4][8];
#pragma unroll
        for (int i = 0; i < 4; ++i)
#pragma unroll
            for (int j = 0; j < 8; ++j) acc[i][j] = 0.f;

        for (int ch = 0; ch < 8; ++ch) {
            const float* Wsrc = (ch < 4) ? W1 : W2;
            int kbase = (ch & 3) * GBK;

#pragma unroll
            for (int it = 0; it < 2; ++it) {
                int idx = tid + it * 256;
                int m = idx >> 3, kq = idx & 7;
                int row = row0 + m;
                float4 v = make_float4(0.f, 0.f, 0.f, 0.f);
                if (row < M) {
                    if (ch < 4) {
                        v = *(const float4*)&aggL[m][kbase + kq * 4];
                    } else {
                        int nr = order[row];
                        int ar = srcmap ? srcmap[nr] : nr;
                        v = *(const float4*)(Hin + (size_t)ar * 128 + kbase + kq * 4);
                    }
                }
                As[kq * 4 + 0][m] = v.x;
                As[kq * 4 + 1][m] = v.y;
                As[kq * 4 + 2][m] = v.z;
                As[kq * 4 + 3][m] = v.w;
            }
#pragma unroll
            for (int it = 0; it < 4; ++it) {
                int idx = tid + it * 256;
                int n = idx >> 3, kq = idx & 7;
                float4 v = *(const float4*)(Wsrc + n * 128 + kbase + kq * 4);
                Ws[kq * 4 + 0][n] = v.x;
                Ws[kq * 4 + 1][n] = v.y;
                Ws[kq * 4 + 2][n] = v.z;
                Ws[kq * 4 + 3][n] = v.w;
            }
            __syncthreads();

#pragma unroll
            for (int kk = 0; kk < GBK; ++kk) {
                float4 a  = *(const float4*)&As[kk][r0];
                float4 w0 = *(const float4*)&Ws[kk][c0];
                float4 w1 = *(const float4*)&Ws[kk][c0 + 64];
                float av[4] = {a.x, a.y, a.z, a.w};
                float wv[8] = {w0.x, w0.y, w0.z, w0.w, w1.x, w1.y, w1.z, w1.w};
#pragma unroll
                for (int i = 0; i < 4; ++i)
#pragma unroll
                    for (int j = 0; j < 8; ++j)
                        acc[i][j] = fmaf(av[i], wv[j], acc[i][j]);
            }
            __syncthreads();
        }

#pragma unroll
        for (int i = 0; i < 4; ++i) {
            int row = row0 + r0 + i;
            if (row >= M) continue;
            int nr = order[row];
            float4 o0, o1;
            o0.x = fmaxf(acc[i][0] + bias[c0 + 0], 0.f);
            o0.y = fmaxf(acc[i][1] + bias[c0 + 1], 0.f);
            o0.z = fmaxf(acc[i][2] + bias[c0 + 2], 0.f);
            o0.w = fmaxf(acc[i][3] + bias[c0 + 3], 0.f);
            o1.x = fmaxf(acc[i][4] + bias[c0 + 64], 0.f);
            o1.y = fmaxf(acc[i][5] + bias[c0 + 65], 0.f);
            o1.z = fmaxf(acc[i][6] + bias[c0 + 66], 0.f);
            o1.w = fmaxf(acc[i][7] + bias[c0 + 67], 0.f);
            *(float4*)(Hout + (size_t)nr * 128 + c0) = o0;
            *(float4*)(Hout + (size_t)nr * 128 + c0 + 64) = o1;
        }

        if (tile == 0 && head_kidx >= 0) {
            dev_head(Hout, W_e1, b_e1, W_e2, b_e2, W_h1, b_h1, W_h2, b_h2,
                     head_out, head_kidx);
        }
        __syncthreads();
    }
}

// ---------------- tail: steps 4,5 (~22 and 2 nodes) + heads + finalize ----------------

__global__ __launch_bounds__(256) void tail_small(
    float* __restrict__ HA, float* __restrict__ HB,
    const int* __restrict__ order, const int* __restrict__ offs,
    const int* __restrict__ csr, const int* __restrict__ cum,
    const float* __restrict__ W_l, const float* __restrict__ b_l,
    const float* __restrict__ W_r,
    const float* __restrict__ W_e1, const float* __restrict__ b_e1,
    const float* __restrict__ W_e2, const float* __restrict__ b_e2,
    const float* __restrict__ W_h1, const float* __restrict__ b_h1,
    const float* __restrict__ W_h2, const float* __restrict__ b_h2,
    float* __restrict__ head_out, float* __restrict__ out) {

    // k=4 on C_1
    dev_aggregate(HA, HB, offs, csr, order, cum[1], nullptr, 0, 1);
    __syncthreads();
    dev_gemm(HB, HA, W_l, W_r, b_l, HA, order, nullptr, nullptr, cum[1], 0, 1,
             W_e1, b_e1, W_e2, b_e2, W_h1, b_h1, W_h2, b_h2, head_out, 3);
    __syncthreads();
    // k=5 on C_0
    dev_aggregate(HA, HB, offs, csr, order, cum[0], nullptr, 0, 1);
    __syncthreads();
    dev_gemm(HB, HA, W_l, W_r, b_l, HA, order, nullptr, nullptr, cum[0], 0, 1,
             W_e1, b_e1, W_e2, b_e2, W_h1, b_h1, W_h2, b_h2, head_out, 4);
    __syncthreads();

    if (threadIdx.x == 0) {
        float a[LMAX];
        float p_not = 1.f, s = 0.f;
        for (int k = 0; k < LMAX; ++k) {
            float p = head_out[2 * k + 1];
            a[k] = p * p_not;
            p_not *= (1.f - p);
            s += a[k];
        }
        float inv = 1.f / (s + 1e-8f);
        float fs = 0.f, ed = 0.f;
        for (int k = 0; k < LMAX; ++k) {
            float al = a[k] * inv;
            out[2 + k] = al;
            fs += al * head_out[2 * k];
            ed += al * (float)(k + 1);
        }
        out[0] = fs;
        out[1] = ed;
    }
}

// ---------------- launch ----------------

extern "C" void kernel_launch(void* const* d_in, const int* in_sizes, int n_in,
                              void* d_out, int out_size, void* d_ws, size_t ws_size,
                              hipStream_t stream) {
    const float* x_full = (const float*)d_in[0];
    const float* W_in  = (const float*)d_in[1];
    const float* b_in  = (const float*)d_in[2];
    const float* W_l   = (const float*)d_in[3];
    const float* b_l   = (const float*)d_in[4];
    const float* W_r   = (const float*)d_in[5];
    const float* W_e1  = (const float*)d_in[6];
    const float* b_e1  = (const float*)d_in[7];
    const float* W_e2  = (const float*)d_in[8];
    const float* b_e2  = (const float*)d_in[9];
    const float* W_h1  = (const float*)d_in[10];
    const float* b_h1  = (const float*)d_in[11];
    const float* W_h2  = (const float*)d_in[12];
    const float* b_h2  = (const float*)d_in[13];
    const int* subset  = (const int*)d_in[14];
    const int* edge    = (const int*)d_in[15];
    const int* esrc = edge;
    const int* edst = edge + E_NUM;

    // workspace carve-up
    char* w = (char*)d_ws;
    float* HA = (float*)w;      w += (size_t)N_SUB * HD * 4;
    float* HB = (float*)w;      w += (size_t)N_SUB * HD * 4;
    int* cnt = (int*)w;         w += (size_t)N_SUB * 4;
    int* offs = (int*)w;        w += (size_t)(N_SUB + 64) * 4;
    int* csr = (int*)w;         w += (size_t)E_NUM * 4;
    int* level = (int*)w;       w += (size_t)N_SUB * 4;
    int* order = (int*)w;       w += (size_t)N_SUB * 4;
    int* cum = (int*)w;         w += 64;
    float* Wc1 = (float*)w;     w += 128 * 128 * 4;
    float* Wc2 = (float*)w;     w += 128 * 128 * 4;
    float* bc = (float*)w;      w += 512;
    float* head_out = (float*)w; w += 256;

    hipMemsetAsync(cnt, 0, (size_t)N_SUB * 4, stream);
    count_deg<<<NB_E, 256, 0, stream>>>(edst, cnt);
    scan_plus<<<1, 1024, 0, stream>>>(cnt, offs, level);
    fill_wcomb<<<NB_E + WCOMB_BLKS, 256, 0, stream>>>(
        esrc, edst, offs, cnt, csr, W_l, W_r, W_in, b_in, b_l, Wc1, Wc2, bc);
    bfs_compact<<<1, 1024, 0, stream>>>(offs, csr, level, order, cum);

    // k=1 on C_4: x_full -> HA (linearity: aggregate raw x, combined weights)
    sage_step<<<512, 256, 0, stream>>>(
        x_full, HA, Wc1, Wc2, bc, order, offs, csr, subset, cum, 4,
        W_e1, b_e1, W_e2, b_e2, W_h1, b_h1, W_h2, b_h2, head_out, 0);
    // k=2 on C_3: HA -> HB
    sage_step<<<48, 256, 0, stream>>>(
        HA, HB, W_l, W_r, b_l, order, offs, csr, nullptr, cum, 3,
        W_e1, b_e1, W_e2, b_e2, W_h1, b_h1, W_h2, b_h2, head_out, 1);
    // k=3 on C_2: HB -> HA
    sage_step<<<4, 256, 0, stream>>>(
        HB, HA, W_l, W_r, b_l, order, offs, csr, nullptr, cum, 2,
        W_e1, b_e1, W_e2, b_e2, W_h1, b_h1, W_h2, b_h2, head_out, 2);
    // k=4,5 + finalize
    tail_small<<<1, 256, 0, stream>>>(
        HA, HB, order, offs, csr, cum,
        W_l, b_l, W_r, W_e1, b_e1, W_e2, b_e2, W_h1, b_h1, W_h2, b_h2,
        head_out, (float*)d_out);
}

// Round 9
// 452.662 us; speedup vs baseline: 1.4703x; 1.4703x over previous
//
#include <hip/hip_runtime.h>
#include <hip/hip_bf16.h>

#define N_FULL 200000
#define N_SUB  80000
#define E_NUM  800000
#define IN_DIM 128
#define HD     128
#define LMAX   5

#define NB_SCAN ((N_SUB + 255) / 256)   // 313
#define NB_E (E_NUM / 256)              // 3125
#define WCOMB_BLKS 128

// ---------------- in-degree count ----------------

__global__ void count_deg(const int* __restrict__ dst, int* __restrict__ cnt) {
    int i = blockIdx.x * blockDim.x + threadIdx.x;
    if (i < E_NUM) atomicAdd(&cnt[dst[i]], 1);
}

// ---------------- multi-block scan: cnt -> offs ----------------

__global__ void scan_block(const int* __restrict__ cnt, int* __restrict__ offs,
                           int* __restrict__ bsums) {
    __shared__ int s[256];
    int t = threadIdx.x;
    int i = blockIdx.x * 256 + t;
    int v = (i < N_SUB) ? cnt[i] : 0;
    s[t] = v;
    __syncthreads();
    for (int off = 1; off < 256; off <<= 1) {
        int x = (t >= off) ? s[t - off] : 0;
        __syncthreads();
        s[t] += x;
        __syncthreads();
    }
    if (i < N_SUB) offs[i] = s[t] - v;
    if (t == 255) bsums[blockIdx.x] = s[255];
}

__global__ void scan_sums(int* __restrict__ bsums) {
    __shared__ int s[512];
    int t = threadIdx.x;
    int v = (t < NB_SCAN) ? bsums[t] : 0;
    s[t] = v;
    __syncthreads();
    for (int off = 1; off < 512; off <<= 1) {
        int x = (t >= off) ? s[t - off] : 0;
        __syncthreads();
        s[t] += x;
        __syncthreads();
    }
    if (t < NB_SCAN) bsums[t] = s[t] - v;
}

// + level init folded in
__global__ void scan_add(int* __restrict__ offs, const int* __restrict__ bsums,
                         int* __restrict__ level) {
    int i = blockIdx.x * 256 + threadIdx.x;
    if (i < N_SUB) {
        offs[i] += bsums[blockIdx.x];
        level[i] = (i < 2) ? 0 : 7;
    }
    if (i == 0) offs[N_SUB] = E_NUM;
}

// ---------------- fill CSR (atomicSub on cnt) + wcomb in spare blocks ----------------
// Wc1 = W_l@W_in, Wc2 = W_r@W_in, bc = (W_l+W_r)@b_in + b_l

__global__ __launch_bounds__(256) void fill_wcomb(
    const int* __restrict__ esrc, const int* __restrict__ edst,
    const int* __restrict__ offs, int* __restrict__ cnt, int* __restrict__ csr,
    const float* __restrict__ W_l, const float* __restrict__ W_r,
    const float* __restrict__ W_in, const float* __restrict__ b_in,
    const float* __restrict__ b_l,
    float* __restrict__ Wc1, float* __restrict__ Wc2, float* __restrict__ bc) {
    int b = blockIdx.x;
    int t = threadIdx.x;
    if (b < NB_E) {
        int i = b * 256 + t;
        int d = edst[i];
        int p = atomicSub(&cnt[d], 1) - 1;   // unique slot in [0, deg)
        csr[offs[d] + p] = esrc[i];
    } else {
        __shared__ float sf[256];
        int f = b - NB_E;                    // 0..127
        if (t < 128) sf[t] = W_l[f * 128 + t];
        else sf[t] = W_r[f * 128 + (t - 128)];
        __syncthreads();
        int c = t & 127, p = t >> 7;
        const float* wrow = p ? (sf + 128) : sf;
        float acc = 0.f;
#pragma unroll 8
        for (int j = 0; j < 128; ++j)
            acc = fmaf(wrow[j], W_in[j * 128 + c], acc);
        (p ? Wc2 : Wc1)[f * 128 + c] = acc;
        if (t < 64) {
            float pa = (sf[t] + sf[128 + t]) * b_in[t] +
                       (sf[t + 64] + sf[192 + t]) * b_in[t + 64];
            for (int off = 32; off; off >>= 1) pa += __shfl_down(pa, off);
            if (t == 0) bc[f] = pa + b_l[f];
        }
    }
}

// ---------------- reverse BFS via CSR, frontier-sparse node-parallel ----------------
// Benign race: all writers in a pass write the same value t+1.

__global__ void bfs_csr(const int* __restrict__ offs, const int* __restrict__ csr,
                        int* __restrict__ level, int t) {
    int i = blockIdx.x * blockDim.x + threadIdx.x;
    if (i >= N_SUB) return;
    if (level[i] != t) return;
    int beg = offs[i], end = offs[i + 1];
    for (int j = beg; j < end; ++j) {
        int u = csr[j];
        if (level[u] > t + 1) level[u] = t + 1;
    }
}

// ---------------- level compaction (multi-block, no global atomics) ----------------

__global__ __launch_bounds__(256) void hist_levels(const int* __restrict__ level,
                                                   int* __restrict__ bhist) {
    __shared__ int h[8];
    int t = threadIdx.x;
    if (t < 8) h[t] = 0;
    __syncthreads();
    int i = blockIdx.x * 256 + t;
    if (i < N_SUB) {
        int l = level[i];
        if (l > 5) l = 6;
        atomicAdd(&h[l], 1);   // LDS atomic only
    }
    __syncthreads();
    if (t < 8) bhist[blockIdx.x * 8 + t] = h[t];
}

__global__ void scan_hist(int* __restrict__ bhist, int* __restrict__ base,
                          int* __restrict__ cum) {
    __shared__ int tot[8];
    int t = threadIdx.x;
    if (t < 8) {
        int acc = 0;
        for (int b = 0; b < NB_SCAN; ++b) {
            int v = bhist[b * 8 + t];
            bhist[b * 8 + t] = acc;
            acc += v;
        }
        tot[t] = acc;
    }
    __syncthreads();
    if (t == 0) {
        int acc = 0;
        for (int l = 0; l <= 5; ++l) {
            base[l] = acc;
            acc += tot[l];
            cum[l] = acc;
        }
    }
}

__global__ __launch_bounds__(256) void emit_order(const int* __restrict__ level,
                                                  const int* __restrict__ bhist,
                                                  const int* __restrict__ base,
                                                  int* __restrict__ order) {
    __shared__ int woff[4][8];
    int t = threadIdx.x;
    int lane = t & 63, wv = t >> 6;
    int i = blockIdx.x * 256 + t;
    int l = 7;
    if (i < N_SUB) {
        l = level[i];
        if (l > 5) l = 6;
    }
    unsigned long long mybal = 0;
#pragma unroll
    for (int q = 0; q < 8; ++q) {
        unsigned long long b = __ballot(l == q);
        if (q == l) mybal = b;
        if (lane == 0) woff[wv][q] = (int)__popcll(b);
    }
    int inrank = (int)__popcll(mybal & ((1ull << lane) - 1ull));
    __syncthreads();
    if (t < 8) {
        int acc = 0;
        for (int w2 = 0; w2 < 4; ++w2) {
            int c = woff[w2][t];
            woff[w2][t] = acc;
            acc += c;
        }
    }
    __syncthreads();
    if (i < N_SUB && l <= 5) {
        int pos = base[l] + bhist[blockIdx.x * 8 + l] + woff[wv][l] + inrank;
        order[pos] = i;
    }
}

// ---------------- mean aggregation over node list (high-occupancy) ----------------
// deg from offs (cnt destroyed by fill_wcomb)

__global__ __launch_bounds__(256) void aggregate_list(
    const float* __restrict__ H, float* __restrict__ Out,
    const int* __restrict__ offs, const int* __restrict__ csr,
    const int* __restrict__ order, const int* __restrict__ cum, int lvl,
    const int* __restrict__ srcmap) {
    int M = cum[lvl];
    int ngroups = (M + 3) >> 2;
    int wid = threadIdx.x >> 6, lane = threadIdx.x & 63;
    for (int g = blockIdx.x; g < ngroups; g += gridDim.x) {
        int ni = g * 4 + wid;
        if (ni >= M) continue;
        int node = order[ni];
        int beg = offs[node], end = offs[node + 1];
        float ax = 0.f, ay = 0.f, bx = 0.f, by = 0.f;
        int j = beg;
        for (; j + 1 < end; j += 2) {
            int s0 = csr[j], s1 = csr[j + 1];
            int r0 = srcmap ? srcmap[s0] : s0;
            int r1 = srcmap ? srcmap[s1] : s1;
            float2 v0 = *(const float2*)(H + (size_t)r0 * HD + lane * 2);
            float2 v1 = *(const float2*)(H + (size_t)r1 * HD + lane * 2);
            ax += v0.x; ay += v0.y;
            bx += v1.x; by += v1.y;
        }
        if (j < end) {
            int s0 = csr[j];
            int r0 = srcmap ? srcmap[s0] : s0;
            float2 v0 = *(const float2*)(H + (size_t)r0 * HD + lane * 2);
            ax += v0.x; ay += v0.y;
        }
        int deg = end - beg;
        float inv = 1.0f / (float)(deg > 1 ? deg : 1);
        *(float2*)(Out + (size_t)node * HD + lane * 2) =
            make_float2((ax + bx) * inv, (ay + by) * inv);
    }
}

// ---------------- head MLP on nodes 0,1 (device fn, 256 threads) ----------------

__device__ void dev_head(
    const float* __restrict__ H,
    const float* __restrict__ W_e1, const float* __restrict__ b_e1,
    const float* __restrict__ W_e2, const float* __restrict__ b_e2,
    const float* __restrict__ W_h1, const float* __restrict__ b_h1,
    const float* __restrict__ W_h2, const float* __restrict__ b_h2,
    float* __restrict__ head_out, int kidx) {

    __shared__ float feat[384];
    __shared__ float rowo[128];
    __shared__ float sc_sh;
    int t = threadIdx.x, lane = t & 63, wv = t >> 6;

    __syncthreads();
    if (t < 128) {
        float a = H[t], b = H[128 + t];
        feat[t] = a;
        feat[128 + t] = b;
        feat[256 + t] = a * b;
    }
    __syncthreads();

    for (int r = wv; r < 128; r += 4) {
        const float* wr = W_e1 + r * 384;
        float acc = 0.f;
#pragma unroll
        for (int j = 0; j < 6; ++j)
            acc += feat[lane + 64 * j] * wr[lane + 64 * j];
        for (int off = 32; off; off >>= 1) acc += __shfl_down(acc, off);
        if (lane == 0) rowo[r] = fmaxf(acc + b_e1[r], 0.f) * W_e2[r];
    }
    __syncthreads();
    if (wv == 0) {
        float v = rowo[lane] + rowo[lane + 64];
        for (int off = 32; off; off >>= 1) v += __shfl_down(v, off);
        if (lane == 0) sc_sh = v + b_e2[0];
    }
    __syncthreads();
    float score = sc_sh;

    for (int r = wv; r < 64; r += 4) {
        const float* wh = W_h1 + r * 257;
        float acc = 0.f;
#pragma unroll
        for (int j = 0; j < 4; ++j)
            acc += feat[lane + 64 * j] * wh[lane + 64 * j];
        if (lane == 0) acc += score * wh[256];
        for (int off = 32; off; off >>= 1) acc += __shfl_down(acc, off);
        if (lane == 0) rowo[r] = fmaxf(acc + b_h1[r], 0.f) * W_h2[r];
    }
    __syncthreads();
    if (wv == 0) {
        float v = rowo[lane];
        for (int off = 32; off; off >>= 1) v += __shfl_down(v, off);
        if (lane == 0) {
            float p = 1.f / (1.f + expf(-(v + b_h2[0])));
            head_out[kidx * 2 + 0] = score;
            head_out[kidx * 2 + 1] = p;
        }
    }
    __syncthreads();
}

// ---------------- fp32 tiled GEMM over node list (+fused head on tile 0) ----------------
// Out[nr][:] = relu( A1[gA(nr)] @ W1.T + A2[gB(nr)] @ W2.T + bias ), nr = order[row]

#define GBM 64
#define GBK 32

__global__ __launch_bounds__(256) void gemm_list(
    const float* __restrict__ A1, const float* __restrict__ A2,
    const float* __restrict__ W1, const float* __restrict__ W2,
    const float* __restrict__ bias, float* __restrict__ Out,
    const int* __restrict__ order, const int* __restrict__ gatherA,
    const int* __restrict__ gatherB, const int* __restrict__ cum, int lvl,
    const float* __restrict__ W_e1, const float* __restrict__ b_e1,
    const float* __restrict__ W_e2, const float* __restrict__ b_e2,
    const float* __restrict__ W_h1, const float* __restrict__ b_h1,
    const float* __restrict__ W_h2, const float* __restrict__ b_h2,
    float* __restrict__ head_out, int head_kidx) {

    __shared__ __align__(16) float As[GBK][68];
    __shared__ __align__(16) float Ws[GBK][132];

    int M = cum[lvl];
    int ntiles = (M + GBM - 1) / GBM;
    int tid = threadIdx.x;
    int tx = tid & 15, ty = tid >> 4;
    int r0 = ty * 4;
    int c0 = tx * 4;

    for (int tile = blockIdx.x; tile < ntiles; tile += gridDim.x) {
        int row0 = tile * GBM;

        float acc[4][8];
#pragma unroll
        for (int i = 0; i < 4; ++i)
#pragma unroll
            for (int j = 0; j < 8; ++j) acc[i][j] = 0.f;

        for (int ch = 0; ch < 8; ++ch) {
            const float* Asrc = (ch < 4) ? A1 : A2;
            const float* Wsrc = (ch < 4) ? W1 : W2;
            const int* gmap = (ch < 4) ? gatherA : gatherB;
            int kbase = (ch & 3) * GBK;

#pragma unroll
            for (int it = 0; it < 2; ++it) {
                int idx = tid + it * 256;
                int m = idx >> 3, kq = idx & 7;
                int row = row0 + m;
                float4 v = make_float4(0.f, 0.f, 0.f, 0.f);
                if (row < M) {
                    int nr = order[row];
                    int ar = gmap ? gmap[nr] : nr;
                    v = *(const float4*)(Asrc + (size_t)ar * 128 + kbase + kq * 4);
                }
                As[kq * 4 + 0][m] = v.x;
                As[kq * 4 + 1][m] = v.y;
                As[kq * 4 + 2][m] = v.z;
                As[kq * 4 + 3][m] = v.w;
            }
#pragma unroll
            for (int it = 0; it < 4; ++it) {
                int idx = tid + it * 256;
                int n = idx >> 3, kq = idx & 7;
                float4 v = *(const float4*)(Wsrc + n * 128 + kbase + kq * 4);
                Ws[kq * 4 + 0][n] = v.x;
                Ws[kq * 4 + 1][n] = v.y;
                Ws[kq * 4 + 2][n] = v.z;
                Ws[kq * 4 + 3][n] = v.w;
            }
            __syncthreads();

#pragma unroll
            for (int kk = 0; kk < GBK; ++kk) {
                float4 a  = *(const float4*)&As[kk][r0];
                float4 w0 = *(const float4*)&Ws[kk][c0];
                float4 w1 = *(const float4*)&Ws[kk][c0 + 64];
                float av[4] = {a.x, a.y, a.z, a.w};
                float wv[8] = {w0.x, w0.y, w0.z, w0.w, w1.x, w1.y, w1.z, w1.w};
#pragma unroll
                for (int i = 0; i < 4; ++i)
#pragma unroll
                    for (int j = 0; j < 8; ++j)
                        acc[i][j] = fmaf(av[i], wv[j], acc[i][j]);
            }
            __syncthreads();
        }

#pragma unroll
        for (int i = 0; i < 4; ++i) {
            int row = row0 + r0 + i;
            if (row >= M) continue;
            int nr = order[row];
            float4 o0, o1;
            o0.x = fmaxf(acc[i][0] + bias[c0 + 0], 0.f);
            o0.y = fmaxf(acc[i][1] + bias[c0 + 1], 0.f);
            o0.z = fmaxf(acc[i][2] + bias[c0 + 2], 0.f);
            o0.w = fmaxf(acc[i][3] + bias[c0 + 3], 0.f);
            o1.x = fmaxf(acc[i][4] + bias[c0 + 64], 0.f);
            o1.y = fmaxf(acc[i][5] + bias[c0 + 65], 0.f);
            o1.z = fmaxf(acc[i][6] + bias[c0 + 66], 0.f);
            o1.w = fmaxf(acc[i][7] + bias[c0 + 67], 0.f);
            *(float4*)(Out + (size_t)nr * 128 + c0) = o0;
            *(float4*)(Out + (size_t)nr * 128 + c0 + 64) = o1;
        }

        // fused head: tile 0 computed rows 0,1 (= nodes 0,1) fully
        if (tile == 0 && head_kidx >= 0) {
            dev_head(Out, W_e1, b_e1, W_e2, b_e2, W_h1, b_h1, W_h2, b_h2,
                     head_out, head_kidx);
        }
    }
}

// ---------------- finalize ----------------

__global__ void finalize(const float* __restrict__ head_out, float* __restrict__ out) {
    if (threadIdx.x == 0 && blockIdx.x == 0) {
        float a[LMAX];
        float p_not = 1.f, s = 0.f;
        for (int k = 0; k < LMAX; ++k) {
            float p = head_out[2 * k + 1];
            a[k] = p * p_not;
            p_not *= (1.f - p);
            s += a[k];
        }
        float inv = 1.f / (s + 1e-8f);
        float fs = 0.f, ed = 0.f;
        for (int k = 0; k < LMAX; ++k) {
            float al = a[k] * inv;
            out[2 + k] = al;
            fs += al * head_out[2 * k];
            ed += al * (float)(k + 1);
        }
        out[0] = fs;
        out[1] = ed;
    }
}

// ---------------- launch ----------------

extern "C" void kernel_launch(void* const* d_in, const int* in_sizes, int n_in,
                              void* d_out, int out_size, void* d_ws, size_t ws_size,
                              hipStream_t stream) {
    const float* x_full = (const float*)d_in[0];
    const float* W_in  = (const float*)d_in[1];
    const float* b_in  = (const float*)d_in[2];
    const float* W_l   = (const float*)d_in[3];
    const float* b_l   = (const float*)d_in[4];
    const float* W_r   = (const float*)d_in[5];
    const float* W_e1  = (const float*)d_in[6];
    const float* b_e1  = (const float*)d_in[7];
    const float* W_e2  = (const float*)d_in[8];
    const float* b_e2  = (const float*)d_in[9];
    const float* W_h1  = (const float*)d_in[10];
    const float* b_h1  = (const float*)d_in[11];
    const float* W_h2  = (const float*)d_in[12];
    const float* b_h2  = (const float*)d_in[13];
    const int* subset  = (const int*)d_in[14];
    const int* edge    = (const int*)d_in[15];
    const int* esrc = edge;
    const int* edst = edge + E_NUM;

    // workspace carve-up
    char* w = (char*)d_ws;
    float* HA = (float*)w;      w += (size_t)N_SUB * HD * 4;
    float* HB = (float*)w;      w += (size_t)N_SUB * HD * 4;
    int* cnt = (int*)w;         w += (size_t)N_SUB * 4;
    int* offs = (int*)w;        w += (size_t)(N_SUB + 64) * 4;
    int* csr = (int*)w;         w += (size_t)E_NUM * 4;
    int* level = (int*)w;       w += (size_t)N_SUB * 4;
    int* order = (int*)w;       w += (size_t)N_SUB * 4;
    int* bsums = (int*)w;       w += 4096;
    int* bhist = (int*)w;       w += (size_t)(NB_SCAN + 1) * 8 * 4;
    int* lvlbase = (int*)w;     w += 64;
    int* cum = (int*)w;         w += 64;
    float* Wc1 = (float*)w;     w += 128 * 128 * 4;
    float* Wc2 = (float*)w;     w += 128 * 128 * 4;
    float* bc = (float*)w;      w += 512;
    float* head_out = (float*)w; w += 256;

    // prep: CSR + combined weights
    hipMemsetAsync(cnt, 0, (size_t)N_SUB * 4, stream);
    count_deg<<<NB_E, 256, 0, stream>>>(edst, cnt);
    scan_block<<<NB_SCAN, 256, 0, stream>>>(cnt, offs, bsums);
    scan_sums<<<1, 512, 0, stream>>>(bsums);
    scan_add<<<NB_SCAN, 256, 0, stream>>>(offs, bsums, level);
    fill_wcomb<<<NB_E + WCOMB_BLKS, 256, 0, stream>>>(
        esrc, edst, offs, cnt, csr, W_l, W_r, W_in, b_in, b_l, Wc1, Wc2, bc);

    // reverse BFS levels 1..4 (frontier-sparse, multi-block)
    for (int t = 0; t < 4; ++t)
        bfs_csr<<<NB_SCAN, 256, 0, stream>>>(offs, csr, level, t);

    // level compaction (multi-block, LDS atomics only)
    hist_levels<<<NB_SCAN, 256, 0, stream>>>(level, bhist);
    scan_hist<<<1, 64, 0, stream>>>(bhist, lvlbase, cum);
    emit_order<<<NB_SCAN, 256, 0, stream>>>(level, bhist, lvlbase, order);

    // k=1 on C_4 (linearity: aggregate raw x, combined weights), head kidx=0
    aggregate_list<<<2048, 256, 0, stream>>>(
        x_full, HB, offs, csr, order, cum, 4, subset);
    gemm_list<<<512, 256, 0, stream>>>(
        HB, x_full, Wc1, Wc2, bc, HA, order, nullptr, subset, cum, 4,
        W_e1, b_e1, W_e2, b_e2, W_h1, b_h1, W_h2, b_h2, head_out, 0);

    // k=2..5 on C_3..C_0 (in-place HA update; agg -> HB each step)
    const int agrid[4] = {96, 64, 8, 1};
    const int ggrid[4] = {64, 4, 1, 1};
    for (int k = 2; k <= LMAX; ++k) {
        int lvl = LMAX - k;
        aggregate_list<<<agrid[k - 2], 256, 0, stream>>>(
            HA, HB, offs, csr, order, cum, lvl, nullptr);
        gemm_list<<<ggrid[k - 2], 256, 0, stream>>>(
            HB, HA, W_l, W_r, b_l, HA, order, nullptr, nullptr, cum, lvl,
            W_e1, b_e1, W_e2, b_e2, W_h1, b_h1, W_h2, b_h2, head_out, k - 1);
    }
    finalize<<<1, 1, 0, stream>>>(head_out, (float*)d_out);
}